// Round 8
// baseline (223.950 us; speedup 1.0000x reference)
//
#include <hip/hip_runtime.h>

// Soft-DTW forward, B=64, N=M=512, gamma=0.1, penalty=0, bandwidth no-op.
// Linear-domain sum-product: E = exp(-d/gamma),
//   E[i][j] = W[i][j]*(E[i-1][j-1] + E[i-1][j] + E[i][j-1]),
//   W = exp2(-D*mask*log2e/gamma).
// 5 waves/block (320 thr): wave 0 = DP consumer (lane t owns cols 8t+1..8t+8,
// 8-ROW macro-steps, systolic skew: step m handles rows 8(m-t)+1..8(m-t)+8).
// Waves 1-4 = W producers: producer q builds 4 rows (q&1 half) of slot
// 2u+3+(q>>1) per super-step into a 4-slot LDS ring (64 KB). Producers load
// at the TOP of each iteration (ping-pong buffer, consumed next iteration),
// so loads are ~1 super-step old at __syncthreads -> vmcnt drain is empty
// (round-6 lesson). Producer work (~350cyc) << consumer -> barriers free.
// Ring safety: consumer reads slots {2u+1,2u+2}, producers write {2u+3,2u+4};
// disjoint mod 4, >=1 barrier between a write and prior tenant's last read.
// Numerics identical to validated rounds 4-7 (per-lane pow2 scale S,
// re-anchored to TARGET_E at max(own chain end, incoming boundary)).
// TARGET_E=-8 @ 8-row cadence: overflow-free and stored-flush-free by
// construction (within-row spread strictly < 2^115.4 since D*mask < 1).

constexpr int Bn = 64, Nn = 512, Mn = 512;
constexpr int TARGET_E = -8;

__device__ __forceinline__ float exp2_fast(float x) {
    float r; asm("v_exp_f32 %0, %1" : "=v"(r) : "v"(x)); return r;
}
__device__ __forceinline__ float log2_fast(float x) {
    float r; asm("v_log_f32 %0, %1" : "=v"(r) : "v"(x)); return r;
}
__device__ __forceinline__ float ldexp_fast(float x, int e) {
    float r; asm("v_ldexp_f32 %0, %1, %2" : "=v"(r) : "v"(x), "v"(e)); return r;
}
__device__ __forceinline__ int frexp_exp(float x) {
    int r; asm("v_frexp_exp_i32_f32 %0, %1" : "=v"(r) : "v"(x)); return r;
}

// Load 4 rows (RBASE..RBASE+3 within the slot tile) of D,mask for slot SLOT.
#define PLOAD4(SLOT, RBASE, BD, BM)                                            \
    {   const int base_ = 8 * ((SLOT) - t) + (RBASE);                          \
        _Pragma("unroll")                                                      \
        for (int rr = 0; rr < 4; ++rr) {                                       \
            int r_ = min(max(base_ + rr, 0), Nn - 1);                          \
            int o_ = r_ * (Mn / 4) + chunk;                                    \
            BD[rr][0] = D4[o_];  BD[rr][1] = D4[o_ + 1];                       \
            BM[rr][0] = M4[o_];  BM[rr][1] = M4[o_ + 1];                       \
        } }

// Build 4 rows of W for slot SLOT from BD/BM and write to the ring.
#define PBUILD4(SLOT, RBASE, BD, BM)                                           \
    {   const int s_ = (SLOT) & 3;                                             \
        _Pragma("unroll")                                                      \
        for (int rr = 0; rr < 4; ++rr) {                                       \
            float4 p_ = BD[rr][0] * BM[rr][0] * negk;                          \
            float4 q_ = BD[rr][1] * BM[rr][1] * negk;                          \
            float4 wa_, wb_;                                                   \
            wa_.x = exp2_fast(p_.x);  wa_.y = exp2_fast(p_.y);                 \
            wa_.z = exp2_fast(p_.z);  wa_.w = exp2_fast(p_.w);                 \
            wb_.x = exp2_fast(q_.x);  wb_.y = exp2_fast(q_.y);                 \
            wb_.z = exp2_fast(q_.z);  wb_.w = exp2_fast(q_.w);                 \
            wlds[s_][2 * ((RBASE) + rr)][t]     = wa_;                         \
            wlds[s_][2 * ((RBASE) + rr) + 1][t] = wb_;                         \
        } }

// Consumer macro-step MM (8 rows): prefetch slot MM+1 -> WNXT, chain with
// WCUR, boundary shfl + max-anchored rescale.
#define CSTEP8(MM, WCUR, WNXT)                                                 \
    {                                                                          \
        const int m_  = (MM);                                                  \
        const int sn_ = (m_ + 1) & 3;                                          \
        _Pragma("unroll")                                                      \
        for (int rr = 0; rr < 8; ++rr) {                                       \
            WNXT[rr][0] = wlds[sn_][2 * rr][t];                                \
            WNXT[rr][1] = wlds[sn_][2 * rr + 1][t];                            \
        }                                                                      \
        if (m_ <= 63) {                                                        \
            if (m_ == t && t != 0) {                                           \
                _Pragma("unroll")                                              \
                for (int c = 0; c < 8; ++c) E[c] = 0.0f;                       \
                Ld = 0.0f;                                                     \
            }                                                                  \
        }                                                                      \
        float ce7_ = 0.0f;                                                     \
        float co_[8];                                                          \
        _Pragma("unroll")                                                      \
        for (int rr = 0; rr < 8; ++rr) {                                       \
            const float Wr_[8] = {                                             \
                WCUR[rr][0].x, WCUR[rr][0].y, WCUR[rr][0].z, WCUR[rr][0].w,    \
                WCUR[rr][1].x, WCUR[rr][1].y, WCUR[rr][1].z, WCUR[rr][1].w };  \
            const float c0s_ = (rr == 0) ? Ld : L[rr - 1];                     \
            float c2_ = L[rr];                                                 \
            float A_[8], Bv_[8];                                               \
            A_[0] = E[0] + c0s_;                                               \
            _Pragma("unroll")                                                  \
            for (int c = 1; c < 8; ++c) A_[c] = E[c] + E[c - 1];               \
            _Pragma("unroll")                                                  \
            for (int c = 0; c < 8; ++c) Bv_[c] = Wr_[c] * A_[c];               \
            _Pragma("unroll")                                                  \
            for (int c = 0; c < 8; ++c) {                                      \
                float nv_ = fmaf(Wr_[c], c2_, Bv_[c]);                         \
                E[c] = nv_;  c2_ = nv_;                                        \
            }                                                                  \
            if (rr == 7) ce7_ = c2_;                                           \
            co_[rr] = __shfl_up(c2_, 1);                                       \
            if (m_ == m_out) {                     /* uniform, rare branch */  \
                if (rr == r_out) {                                             \
                    float sel_ = E[0];                                         \
                    if (c_out == 1) sel_ = E[1];  if (c_out == 2) sel_ = E[2]; \
                    if (c_out == 3) sel_ = E[3];  if (c_out == 4) sel_ = E[4]; \
                    if (c_out == 5) sel_ = E[5];  if (c_out == 6) sel_ = E[6]; \
                    if (c_out == 7) sel_ = E[7];                               \
                    ov = sel_;  ovS = S;                                       \
                }                                                              \
            }                                                                  \
        }                                                                      \
        int So_ = __shfl_up(S, 1);                                             \
        int eo_ = frexp_exp(ce7_);                                             \
        int ei_ = frexp_exp(co_[7]) + (So_ - S);                               \
        bool own0_  = (ce7_ == 0.0f);                                          \
        bool incok_ = (t != 0) && (co_[7] != 0.0f);                            \
        int  eref_  = (incok_ && ((ei_ > eo_) || own0_)) ? ei_ : eo_;          \
        int  shift_ = (own0_ && !incok_) ? 0 : (TARGET_E - eref_);             \
        if (m_ < t) shift_ = S - So_;          /* virgin: adopt sender */      \
        int Snew_ = S - shift_;                                                \
        _Pragma("unroll")                                                      \
        for (int c = 0; c < 8; ++c) E[c] = ldexp_fast(E[c], shift_);           \
        Ld = ldexp_fast(L[7], shift_);                                         \
        {   int d_ = So_ - Snew_;                                              \
            _Pragma("unroll")                                                  \
            for (int rr = 0; rr < 8; ++rr)                                     \
                L[rr] = (t == 0) ? 0.0f : ldexp_fast(co_[rr], d_);             \
        }                                                                      \
        S = Snew_;                                                             \
    }

__global__ __launch_bounds__(320, 1) void softdtw_fwd(
    const float* __restrict__ D, const float* __restrict__ Msk,
    const int* __restrict__ xlens, const int* __restrict__ ylens,
    float* __restrict__ out)
{
    const int tid = threadIdx.x;
    const int w   = tid >> 6;                   // 0 = consumer, 1..4 = producers
    const int t   = tid & 63;
    const int b   = blockIdx.x;
    const int xl = xlens[b];
    const int yl = ylens[b];
    const int t_out = (yl - 1) >> 3;
    const int c_out = (yl - 1) & 7;
    const int r_out = (xl - 1) & 7;
    const int m_out = ((xl - 1) >> 3) + t_out;
    const int nsuper = (m_out >> 1) + 1;

    const float negk = -14.4269504088896341f;   // -log2(e)/gamma
    const float klog = 0.06931471805599453f;    // gamma*ln2

    __shared__ float4 wlds[4][16][64];          // 4-slot ring, 64 KiB exactly

    const float4* __restrict__ D4 = (const float4*)(D   + (size_t)b * (Nn * Mn));
    const float4* __restrict__ M4 = (const float4*)(Msk + (size_t)b * (Nn * Mn));
    const int chunk = t * 2;

    // consumer state
    float E[8];
#pragma unroll
    for (int c = 0; c < 8; ++c) E[c] = 0.0f;
    float L[8] = {0.0f, 0.0f, 0.0f, 0.0f, 0.0f, 0.0f, 0.0f, 0.0f};
    float Ld = (t == 0) ? 1.0f : 0.0f;          // E(d[0][0]) = 1
    int S = 0;
    float ov = 1.0f;  int ovS = 0;
    float4 Wc[8][2], Wn[8][2];

    // producer state
    const int q    = w - 1;                     // 0..3
    const int half = (q & 1) * 4;               // row base within slot
    const int ss   = q >> 1;                    // which of the 2 slots/super-step
    float4 bD0[4][2], bM0[4][2], bD1[4][2], bM1[4][2];

    if (w != 0) {
        if (q < 3) {                            // prologue: slots 0..2 (full 8 rows each)
            PLOAD4(q, 0, bD0, bM0);  PBUILD4(q, 0, bD0, bM0);
            PLOAD4(q, 4, bD0, bM0);  PBUILD4(q, 4, bD0, bM0);
        }
        PLOAD4(3 + ss, half, bD1, bM1);         // prime: built at u=0
    }
    __syncthreads();

    if (w == 0) {
#pragma unroll
        for (int rr = 0; rr < 8; ++rr) {
            Wc[rr][0] = wlds[0][2 * rr][t];
            Wc[rr][1] = wlds[0][2 * rr + 1][t];
        }
    }

    for (int u = 0; u < nsuper; ++u) {
        if (w == 0) {
            CSTEP8(2 * u, Wc, Wn);
            if (2 * u + 1 <= m_out) CSTEP8(2 * u + 1, Wn, Wc);
        } else {
            // load (top of iter, consumed next iter) then build (loaded last iter)
            if (u & 1) { PLOAD4(2 * u + 5 + ss, half, bD1, bM1);
                         PBUILD4(2 * u + 3 + ss, half, bD0, bM0); }
            else       { PLOAD4(2 * u + 5 + ss, half, bD0, bM0);
                         PBUILD4(2 * u + 3 + ss, half, bD1, bM1); }
        }
        __syncthreads();
    }

    if (w == 0 && t == t_out) {
        int   ev = frexp_exp(ov);
        float mv = ldexp_fast(ov, -ev);         // normal mantissa in [0.5,1)
        out[b] = -(log2_fast(mv) + (float)(ev + ovS)) * klog;
    }
}

extern "C" void kernel_launch(void* const* d_in, const int* in_sizes, int n_in,
                              void* d_out, int out_size, void* d_ws, size_t ws_size,
                              hipStream_t stream) {
    const float* D   = (const float*)d_in[0];
    const float* Msk = (const float*)d_in[1];
    const int*   xl  = (const int*)d_in[2];
    const int*   yl  = (const int*)d_in[3];
    float* out = (float*)d_out;
    softdtw_fwd<<<dim3(Bn), dim3(320), 0, stream>>>(D, Msk, xl, yl, out);
}

// Round 9
// 155.524 us; speedup vs baseline: 1.4400x; 1.4400x over previous
//
#include <hip/hip_runtime.h>

// Soft-DTW forward, B=64, N=M=512, gamma=0.1, penalty=0, bandwidth no-op.
// Linear-domain sum-product: E = exp(-d/gamma),
//   E[i][j] = W[i][j]*(E[i-1][j-1] + E[i-1][j] + E[i][j-1]),
//   W = exp2(-D*mask*log2e/gamma).
// 3 waves/block: wave 0 = DP consumer (lane t owns cols 8t+1..8t+8, 4-row
// macro-steps, systolic skew), waves 1,2 = W producers -> 6-slot LDS ring.
// Fixes vs r6 (which tied the monolithic kernel):
//  (a) producers load at the TOP of iteration u the rows built at u+1
//      (ping-pong reg buffers) -> loads are a full super-step old at
//      __syncthreads, so its vmcnt(0) drain is empty (r6/r8 lesson);
//  (b) consumer prefetches next W tile at the END of its step, after the
//      shfls: LDS ops retire in-order, so prefetch ds_reads issued before
//      the shfls would have to drain before the shfl result arrives,
//      serializing prefetch into the chain (r6 stall diagnosis).
// Ring safety (mod 6): super-step u: consumer chains slots {2u,2u+1} and
// prefetches {2u+1,2u+2}; producers write {2u+4,2u+5} -- disjoint.
// Previous tenant of a slot written at u was last touched in super u-1.
// Numerics identical to rounds 5-7 (per-lane pow2 scale S re-anchored to
// TARGET_E at max(own chain end, incoming boundary); all passed absmax 0).

constexpr int Bn = 64, Nn = 512, Mn = 512;
constexpr int TARGET_E = -30;

__device__ __forceinline__ float exp2_fast(float x) {
    float r; asm("v_exp_f32 %0, %1" : "=v"(r) : "v"(x)); return r;
}
__device__ __forceinline__ float log2_fast(float x) {
    float r; asm("v_log_f32 %0, %1" : "=v"(r) : "v"(x)); return r;
}
__device__ __forceinline__ float ldexp_fast(float x, int e) {
    float r; asm("v_ldexp_f32 %0, %1, %2" : "=v"(r) : "v"(x), "v"(e)); return r;
}
__device__ __forceinline__ int frexp_exp(float x) {
    int r; asm("v_frexp_exp_i32_f32 %0, %1" : "=v"(r) : "v"(x)); return r;
}

// Load 4 rows (D,mask) for macro-step/slot MM into register buffers BD/BM.
#define PLOAD(MM, BD, BM)                                                      \
    {   const int base_ = 4 * ((MM) - t);                                      \
        _Pragma("unroll")                                                      \
        for (int rr = 0; rr < 4; ++rr) {                                       \
            int r_ = min(max(base_ + rr, 0), Nn - 1);                          \
            int o_ = r_ * (Mn / 4) + chunk;                                    \
            BD[rr][0] = D4[o_];  BD[rr][1] = D4[o_ + 1];                       \
            BM[rr][0] = M4[o_];  BM[rr][1] = M4[o_ + 1];                       \
        } }

// Build W tile for slot MM from BD/BM and write it to the ring.
#define PBUILD(MM, BD, BM)                                                     \
    {   const int s_ = (MM) % 6;                                               \
        _Pragma("unroll")                                                      \
        for (int rr = 0; rr < 4; ++rr) {                                       \
            float4 p_ = BD[rr][0] * BM[rr][0] * negk;                          \
            float4 q_ = BD[rr][1] * BM[rr][1] * negk;                          \
            float4 wa_, wb_;                                                   \
            wa_.x = exp2_fast(p_.x);  wa_.y = exp2_fast(p_.y);                 \
            wa_.z = exp2_fast(p_.z);  wa_.w = exp2_fast(p_.w);                 \
            wb_.x = exp2_fast(q_.x);  wb_.y = exp2_fast(q_.y);                 \
            wb_.z = exp2_fast(q_.z);  wb_.w = exp2_fast(q_.w);                 \
            wlds[s_][2 * rr][t]     = wa_;                                     \
            wlds[s_][2 * rr + 1][t] = wb_;                                     \
        } }

// Consumer macro-step MM: chain with WCUR, boundary shfl + rescale, THEN
// prefetch slot MM+1 into WNXT (ds_reads retire during next step's chain).
#define CSTEP(MM, WCUR, WNXT)                                                  \
    {                                                                          \
        const int m_ = (MM);                                                   \
        if (m_ <= 63) {                                                        \
            if (m_ == t && t != 0) {                                           \
                _Pragma("unroll")                                              \
                for (int c = 0; c < 8; ++c) E[c] = 0.0f;                       \
                Ld = 0.0f;                                                     \
            }                                                                  \
        }                                                                      \
        float ce3_, co_[4];                                                    \
        _Pragma("unroll")                                                      \
        for (int rr = 0; rr < 4; ++rr) {                                       \
            const float Wr_[8] = {                                             \
                WCUR[rr][0].x, WCUR[rr][0].y, WCUR[rr][0].z, WCUR[rr][0].w,    \
                WCUR[rr][1].x, WCUR[rr][1].y, WCUR[rr][1].z, WCUR[rr][1].w };  \
            const float c0s_ = (rr == 0) ? Ld : L[rr - 1];                     \
            float c2_ = L[rr];                                                 \
            float A_[8], Bv_[8];                                               \
            A_[0] = E[0] + c0s_;                                               \
            _Pragma("unroll")                                                  \
            for (int c = 1; c < 8; ++c) A_[c] = E[c] + E[c - 1];               \
            _Pragma("unroll")                                                  \
            for (int c = 0; c < 8; ++c) Bv_[c] = Wr_[c] * A_[c];               \
            _Pragma("unroll")                                                  \
            for (int c = 0; c < 8; ++c) {                                      \
                float nv_ = fmaf(Wr_[c], c2_, Bv_[c]);                         \
                E[c] = nv_;  c2_ = nv_;                                        \
            }                                                                  \
            if (rr == 3) ce3_ = c2_;                                           \
            co_[rr] = __shfl_up(c2_, 1);                                       \
            if (m_ == m_out && rr == r_out) {   /* uniform: taken once */      \
                float sel_ = E[0];                                             \
                if (c_out == 1) sel_ = E[1];  if (c_out == 2) sel_ = E[2];     \
                if (c_out == 3) sel_ = E[3];  if (c_out == 4) sel_ = E[4];     \
                if (c_out == 5) sel_ = E[5];  if (c_out == 6) sel_ = E[6];     \
                if (c_out == 7) sel_ = E[7];                                   \
                ov = sel_;  ovS = S;                                           \
            }                                                                  \
        }                                                                      \
        int So_ = __shfl_up(S, 1);                                             \
        int eo_ = frexp_exp(ce3_);                                             \
        int ei_ = frexp_exp(co_[3]) + (So_ - S);                               \
        bool own0_  = (ce3_ == 0.0f);                                          \
        bool incok_ = (t != 0) && (co_[3] != 0.0f);                            \
        int  eref_  = (incok_ && ((ei_ > eo_) || own0_)) ? ei_ : eo_;          \
        int  shift_ = (own0_ && !incok_) ? 0 : (TARGET_E - eref_);             \
        if (m_ < t) shift_ = S - So_;          /* virgin: adopt sender */      \
        int Snew_ = S - shift_;                                                \
        _Pragma("unroll")                                                      \
        for (int c = 0; c < 8; ++c) E[c] = ldexp_fast(E[c], shift_);           \
        Ld = ldexp_fast(L[3], shift_);                                         \
        {   int d_ = So_ - Snew_;                                              \
            _Pragma("unroll")                                                  \
            for (int rr = 0; rr < 4; ++rr)                                     \
                L[rr] = (t == 0) ? 0.0f : ldexp_fast(co_[rr], d_);             \
        }                                                                      \
        S = Snew_;                                                             \
        {   const int sn_ = (m_ + 1) % 6;      /* prefetch LAST (in-order DS) */ \
            _Pragma("unroll")                                                  \
            for (int rr = 0; rr < 4; ++rr) {                                   \
                WNXT[rr][0] = wlds[sn_][2 * rr][t];                            \
                WNXT[rr][1] = wlds[sn_][2 * rr + 1][t];                        \
            } }                                                                \
    }

__global__ __launch_bounds__(192) void softdtw_fwd(
    const float* __restrict__ D, const float* __restrict__ Msk,
    const int* __restrict__ xlens, const int* __restrict__ ylens,
    float* __restrict__ out)
{
    const int tid = threadIdx.x;
    const int w   = tid >> 6;                   // 0 = consumer, 1/2 = producers
    const int t   = tid & 63;
    const int b   = blockIdx.x;
    const int xl = xlens[b];
    const int yl = ylens[b];
    const int t_out = (yl - 1) >> 3;
    const int c_out = (yl - 1) & 7;
    const int r_out = (xl - 1) & 3;
    const int m_out = ((xl - 1) >> 2) + t_out;
    const int nsuper = (m_out >> 1) + 1;

    const float negk = -14.4269504088896341f;   // -log2(e)/gamma
    const float klog = 0.06931471805599453f;    // gamma*ln2

    __shared__ float4 wlds[6][8][64];           // 48 KiB W ring

    const float4* __restrict__ D4 = (const float4*)(D   + (size_t)b * (Nn * Mn));
    const float4* __restrict__ M4 = (const float4*)(Msk + (size_t)b * (Nn * Mn));
    const int chunk = t * 2;

    // consumer state
    float E[8];
#pragma unroll
    for (int c = 0; c < 8; ++c) E[c] = 0.0f;
    float L[4] = {0.0f, 0.0f, 0.0f, 0.0f};
    float Ld = (t == 0) ? 1.0f : 0.0f;          // E(d[0][0]) = 1
    int S = 0;
    float ov = 1.0f;  int ovS = 0;
    float4 Wc[4][2], Wn[4][2];

    // producer state: ping-pong load buffers (loads issued one iter early)
    const int p = w - 1;
    float4 bD0[4][2], bM0[4][2], bD1[4][2], bM1[4][2];

    if (w != 0) {
        // prologue: build slots p, p+2 (serial, latency uncritical);
        // prime buf1 with the rows for slot 4+p (built at u=0).
        PLOAD(p, bD0, bM0);      PBUILD(p, bD0, bM0);
        PLOAD(p + 2, bD0, bM0);  PBUILD(p + 2, bD0, bM0);
        PLOAD(4 + p, bD1, bM1);
    }
    __syncthreads();

    if (w == 0) {
#pragma unroll
        for (int rr = 0; rr < 4; ++rr) {
            Wc[rr][0] = wlds[0][2 * rr][t];
            Wc[rr][1] = wlds[0][2 * rr + 1][t];
        }
    }

    for (int u = 0; u < nsuper; ++u) {
        if (w == 0) {
            CSTEP(2 * u, Wc, Wn);
            if (2 * u + 1 <= m_out) CSTEP(2 * u + 1, Wn, Wc);
        } else {
            // loads at TOP (for next iter's build); build from last iter's loads
            if (u & 1) { PLOAD(2 * u + 6 + p, bD1, bM1);
                         PBUILD(2 * u + 4 + p, bD0, bM0); }
            else       { PLOAD(2 * u + 6 + p, bD0, bM0);
                         PBUILD(2 * u + 4 + p, bD1, bM1); }
        }
        __syncthreads();
    }

    if (w == 0 && t == t_out) {
        int   ev = frexp_exp(ov);
        float mv = ldexp_fast(ov, -ev);         // normal mantissa in [0.5,1)
        out[b] = -(log2_fast(mv) + (float)(ev + ovS)) * klog;
    }
}

extern "C" void kernel_launch(void* const* d_in, const int* in_sizes, int n_in,
                              void* d_out, int out_size, void* d_ws, size_t ws_size,
                              hipStream_t stream) {
    const float* D   = (const float*)d_in[0];
    const float* Msk = (const float*)d_in[1];
    const int*   xl  = (const int*)d_in[2];
    const int*   yl  = (const int*)d_in[3];
    float* out = (float*)d_out;
    softdtw_fwd<<<dim3(Bn), dim3(192), 0, stream>>>(D, Msk, xl, yl, out);
}